// Round 5
// baseline (1417.844 us; speedup 1.0000x reference)
//
#include <hip/hip_runtime.h>
#include <math.h>
#include <stdint.h>

// Autoregressive flow via MFMA (bf16):
//   D[j][batch] = W[j][:] . h[batch][:]   (A-frag = weight rows, B-frag = h cols)
// GRU gates via 16x16x32 bf16 MFMA; y/bias enter through a sparse "ks2" slice
// (B-rows k=0..2 = [y.x, y.y, 1], nonzero only on g==0 lanes -> A-frag on g>0
// lanes is don't-care => uniform broadcast addressing, no masks).
// h kept fp32 in regs (D-layout) for the u*h memory path; bf16 h round-trips
// through per-wave LDS to convert D-layout -> B-frag layout.
// Round 5: (a) RZN weights re-loaded from global (L1-hot) each step via an
// anti-hoist pointer -> frees ~96 VGPRs -> 3 blocks/CU (launch_bounds(256,3));
// (b) log2e prescaled into R/Z (x -log2e) and N/I (x 2*log2e) weight rows so
// sigmoid/tanh consume MFMA outputs directly via exp2f (native v_exp_f32).

typedef short bf16x8 __attribute__((ext_vector_type(8)));
typedef float f32x4  __attribute__((ext_vector_type(4)));

// workspace layout (shorts)
#define OFF_RZN 0          // [192][64]  Whh rows (R,Z,N), prescaled
#define OFF_KS2 12288      // [4][64][8] sets R,Z,N,I: (Wih0, Wih1, bias, 0...), prescaled
#define OFF_W2F 14336      // [64][8]    per-lane W2 A-frag (rows padded 4->16)
#define OFF_W1P 14848      // [32][72]   W1 padded rows
#define WS_TOT  17152

#define W1LDW 72           // 144 B rows
#define HLW   104          // 208 B rows
#define XYW   28           // 112 B rows

#define SCL_RZ (-1.4426950408889634f)   // -log2(e)
#define SCL_NI ( 2.8853900817779268f)   // 2*log2(e)

__device__ __forceinline__ short f2bf(float f) {
    union { float f; uint32_t u; } v; v.f = f;
    uint32_t r = v.u + 0x7fffu + ((v.u >> 16) & 1u);
    return (short)(r >> 16);
}
__device__ __forceinline__ uint32_t cvtpk(float lo, float hi) {
    uint32_t r;
    asm("v_cvt_pk_bf16_f32 %0, %1, %2" : "=v"(r) : "v"(lo), "v"(hi));
    return r;
}
__device__ __forceinline__ float rcpf(float x) { return __builtin_amdgcn_rcpf(x); }
__device__ __forceinline__ float softplusf(float x) {
    return fmaxf(x, 0.f) + __logf(1.f + __expf(-fabsf(x)));
}

// ---------------- weight prep (with log2e prescale) ----------------
__global__ void prep_kernel(const float* __restrict__ Wih, const float* __restrict__ Whh,
                            const float* __restrict__ bih, const float* __restrict__ bhh,
                            const float* __restrict__ W1, const float* __restrict__ W2,
                            short* __restrict__ wsw) {
    int idx = blockIdx.x * blockDim.x + threadIdx.x;
    if (idx >= WS_TOT) return;
    float v = 0.f;
    if (idx < OFF_KS2) {
        int row = idx >> 6;
        float s = (row < 128) ? SCL_RZ : SCL_NI;
        v = Whh[idx] * s;
    } else if (idx < OFF_W2F) {
        int i = idx - OFF_KS2;
        int s = i >> 9, r = (i >> 3) & 63, j = i & 7;
        float sc = (s < 2) ? SCL_RZ : SCL_NI;
        if (s == 0) {            // R
            if (j == 0) v = Wih[2 * r];
            else if (j == 1) v = Wih[2 * r + 1];
            else if (j == 2) v = bih[r] + bhh[r];
        } else if (s == 1) {     // Z
            int row = 64 + r;
            if (j == 0) v = Wih[2 * row];
            else if (j == 1) v = Wih[2 * row + 1];
            else if (j == 2) v = bih[row] + bhh[row];
        } else if (s == 2) {     // N (bias bhh_n only; multiplied by r later)
            if (j == 2) v = bhh[128 + r];
        } else {                 // I (i_n = Wih_n.y + bih_n)
            int row = 128 + r;
            if (j == 0) v = Wih[2 * row];
            else if (j == 1) v = Wih[2 * row + 1];
            else if (j == 2) v = bih[row];
        }
        v *= sc;
    } else if (idx < OFF_W1P) {
        int i = idx - OFF_W2F;
        int l = i >> 3, j = i & 7;
        int lnn = l & 15, gg = l >> 4;
        v = (lnn < 4) ? W2[lnn * 32 + gg * 8 + j] : 0.f;
    } else {
        int i = idx - OFF_W1P;
        int r = i / W1LDW, c = i - r * W1LDW;
        v = (c < 64) ? W1[r * 64 + c] : 0.f;
    }
    wsw[idx] = f2bf(v);
}

// ---------------- main kernel: 4 waves/block, 32 rows/wave, 3 blocks/CU ----------------
__global__ __launch_bounds__(256, 3)
void arflow5(const float* __restrict__ y_tm1,
             const float* __restrict__ z,
             const float* __restrict__ x,
             const float* __restrict__ b1,
             const float* __restrict__ b2,
             const short* __restrict__ wsw,
             float* __restrict__ out,
             int B, int T)
{
    __shared__ __align__(16) float XY[128 * XYW];        // 14336 B (x, overwritten by y)
    __shared__ __align__(16) short HL[4][32 * HLW];      // 26624 B (per-wave h + a)
    __shared__ __align__(16) short KS2[4 * 64 * 8];      //  4096 B
    __shared__ __align__(16) short W1L[32 * W1LDW];      //  4608 B

    const int tid  = threadIdx.x;
    const int wave = tid >> 6;
    const int lane = tid & 63;
    const int g    = lane >> 4;
    const int ln   = lane & 15;
    const int base = blockIdx.x * 128;
    const int rows = (B - base < 128) ? (B - base) : 128;
    const int NF4  = T >> 1;   // float4s per x-row (T*2/4)
    const bool g0  = (g == 0);

    // ---- stage x -> XY (coalesced) ----
    {
        const float4* xg = reinterpret_cast<const float4*>(x) + (size_t)base * NF4;
        const int tot = 128 * NF4;
        for (int i = tid; i < tot; i += 256) {
            float4 v = (i < rows * NF4) ? xg[i] : make_float4(0.f, 0.f, 0.f, 0.f);
            int r = i / NF4, c = i - r * NF4;
            *reinterpret_cast<float4*>(&XY[r * XYW + c * 4]) = v;
        }
    }
    // ---- stage KS2 + W1L ----
    {
        const uint32_t* src = reinterpret_cast<const uint32_t*>(wsw + OFF_KS2);
        uint32_t* dst = reinterpret_cast<uint32_t*>(KS2);
        for (int i = tid; i < 1024; i += 256) dst[i] = src[i];
        const uint32_t* s1 = reinterpret_cast<const uint32_t*>(wsw + OFF_W1P);
        uint32_t* d1 = reinterpret_cast<uint32_t*>(W1L);
        for (int i = tid; i < (32 * W1LDW) / 2; i += 256) d1[i] = s1[i];
    }

    bf16x8 w2f = *reinterpret_cast<const bf16x8*>(wsw + OFF_W2F + lane * 8);

    f32x4 b1q[2];
#pragma unroll
    for (int mt = 0; mt < 2; ++mt) {
        float4 tv = reinterpret_cast<const float4*>(b1)[mt * 4 + g];
        b1q[mt][0] = tv.x; b1q[mt][1] = tv.y; b1q[mt][2] = tv.z; b1q[mt][3] = tv.w;
    }
    const float b20 = b2[0], b21 = b2[1], b22 = b2[2], b23 = b2[3];
    const f32x4 Z0 = {0.f, 0.f, 0.f, 0.f};

    // ---- init h (from z, fp32 regs in D-layout), y ----
    float hpr[4][2][4];
    float2 y[2];
    short* hl = &HL[wave][0];
#pragma unroll
    for (int n = 0; n < 2; ++n) {
        int gr = base + wave * 32 + n * 16 + ln;
        bool ok = gr < B;
#pragma unroll
        for (int mg = 0; mg < 4; ++mg) {
            float4 zv = ok ? reinterpret_cast<const float4*>(z)[(size_t)gr * 16 + mg * 4 + g]
                           : make_float4(0.f, 0.f, 0.f, 0.f);
            hpr[mg][n][0] = zv.x; hpr[mg][n][1] = zv.y;
            hpr[mg][n][2] = zv.z; hpr[mg][n][3] = zv.w;
        }
        float2 yv = ok ? reinterpret_cast<const float2*>(y_tm1)[gr] : make_float2(0.f, 0.f);
        y[n] = yv;
    }
    // initial h -> hl (bf16, D-layout store), read initial B-frags
#pragma unroll
    for (int n = 0; n < 2; ++n)
#pragma unroll
        for (int mg = 0; mg < 4; ++mg) {
            uint2 pk;
            pk.x = cvtpk(hpr[mg][n][0], hpr[mg][n][1]);
            pk.y = cvtpk(hpr[mg][n][2], hpr[mg][n][3]);
            *reinterpret_cast<uint2*>(&hl[(n * 16 + ln) * HLW + mg * 16 + g * 4]) = pk;
        }
    bf16x8 hb[2][2];
#pragma unroll
    for (int n = 0; n < 2; ++n)
#pragma unroll
        for (int ks = 0; ks < 2; ++ks)
            hb[n][ks] = *reinterpret_cast<const bf16x8*>(&hl[(n * 16 + ln) * HLW + ks * 32 + g * 8]);

    __syncthreads();

    const uint32_t onepk = g0 ? 0x00003F80u : 0u;   // bf16(1.0) in elem slot 2
    // uniform KS2 base: g>0 lanes read real data but it multiplies zero B-rows
    const volatile bf16x8* k2p = reinterpret_cast<const volatile bf16x8*>(&KS2[ln * 8]);
    const volatile bf16x8* w1p = reinterpret_cast<const volatile bf16x8*>(&W1L[ln * W1LDW + g * 8]);

    // anti-hoist pointer for per-step weight reloads (keeps them out of regs
    // across the loop; loads hit L1 -- 24 KB hot working set)
    const short* wp = wsw;
    const int woff = ln * 8 + g;   // bf16x8 index of this lane's frag base

    for (int t = 0; t < T; ++t) {
        asm volatile("" : "+s"(wp));

        // ks2 B-frags: k=0..2 = [y.x, y.y, 1] on g==0 lanes, else 0
        bf16x8 yb[2];
#pragma unroll
        for (int n = 0; n < 2; ++n) {
            uint32_t ypk = cvtpk(y[n].x, y[n].y);
            union { bf16x8 v; uint32_t u[4]; } yu;
            yu.u[0] = g0 ? ypk : 0u;
            yu.u[1] = onepk;
            yu.u[2] = 0u; yu.u[3] = 0u;
            yb[n] = yu.v;
        }

        // ---- GRU: per (mg, n); weights re-loaded per mg (L1-hot) ----
#pragma unroll
        for (int mg = 0; mg < 4; ++mg) {
            asm volatile("" : "+s"(wp));   // group loads per-mg (limit regs in flight)
            const bf16x8* wq = reinterpret_cast<const bf16x8*>(wp) + woff;
            bf16x8 wR0 = wq[(0 * 64 + mg * 16) * 8 + 0];
            bf16x8 wR1 = wq[(0 * 64 + mg * 16) * 8 + 4];
            bf16x8 wZ0 = wq[(1 * 64 + mg * 16) * 8 + 0];
            bf16x8 wZ1 = wq[(1 * 64 + mg * 16) * 8 + 4];
            bf16x8 wN0 = wq[(2 * 64 + mg * 16) * 8 + 0];
            bf16x8 wN1 = wq[(2 * 64 + mg * 16) * 8 + 4];
            bf16x8 k2R = k2p[0 * 64 + mg * 16];
            bf16x8 k2Z = k2p[1 * 64 + mg * 16];
            bf16x8 k2N = k2p[2 * 64 + mg * 16];
            bf16x8 k2I = k2p[3 * 64 + mg * 16];
#pragma unroll
            for (int n = 0; n < 2; ++n) {
                f32x4 aR = __builtin_amdgcn_mfma_f32_16x16x32_bf16(wR0, hb[n][0], Z0, 0, 0, 0);
                f32x4 aZ = __builtin_amdgcn_mfma_f32_16x16x32_bf16(wZ0, hb[n][0], Z0, 0, 0, 0);
                f32x4 aN = __builtin_amdgcn_mfma_f32_16x16x32_bf16(wN0, hb[n][0], Z0, 0, 0, 0);
                f32x4 aI = __builtin_amdgcn_mfma_f32_16x16x32_bf16(k2I, yb[n],    Z0, 0, 0, 0);
                aR = __builtin_amdgcn_mfma_f32_16x16x32_bf16(wR1, hb[n][1], aR, 0, 0, 0);
                aZ = __builtin_amdgcn_mfma_f32_16x16x32_bf16(wZ1, hb[n][1], aZ, 0, 0, 0);
                aN = __builtin_amdgcn_mfma_f32_16x16x32_bf16(wN1, hb[n][1], aN, 0, 0, 0);
                aR = __builtin_amdgcn_mfma_f32_16x16x32_bf16(k2R, yb[n], aR, 0, 0, 0);
                aZ = __builtin_amdgcn_mfma_f32_16x16x32_bf16(k2Z, yb[n], aZ, 0, 0, 0);
                aN = __builtin_amdgcn_mfma_f32_16x16x32_bf16(k2N, yb[n], aN, 0, 0, 0);

                // gates: aR/aZ pre-scaled by -log2e, aN/aI by 2*log2e
                float hq[4];
#pragma unroll
                for (int q = 0; q < 4; ++q) {
                    float r  = rcpf(1.f + exp2f(aR[q]));
                    float u  = rcpf(1.f + exp2f(aZ[q]));
                    float ee = exp2f(fmaf(r, aN[q], aI[q]));
                    float nn = fmaf(-2.f, rcpf(ee + 1.f), 1.f);
                    float hv = fmaf(u, hpr[mg][n][q] - nn, nn);   // (1-u)*n + u*h
                    hpr[mg][n][q] = hv;
                    hq[q] = hv;
                }
                uint2 pk;
                pk.x = cvtpk(hq[0], hq[1]);
                pk.y = cvtpk(hq[2], hq[3]);
                *reinterpret_cast<uint2*>(&hl[(n * 16 + ln) * HLW + mg * 16 + g * 4]) = pk;
            }
        }

        // ---- re-read h' B-frags (used by MLP1 now and GRU next step) ----
#pragma unroll
        for (int n = 0; n < 2; ++n)
#pragma unroll
            for (int ks = 0; ks < 2; ++ks)
                hb[n][ks] = *reinterpret_cast<const bf16x8*>(&hl[(n * 16 + ln) * HLW + ks * 32 + g * 8]);

        // ---- MLP1 via MFMA (b1 as C-operand) ----
        f32x4 aM[2][2];
#pragma unroll
        for (int mt = 0; mt < 2; ++mt) {
            bf16x8 wM0 = w1p[mt * 16 * (W1LDW / 8) + 0];
            bf16x8 wM1 = w1p[mt * 16 * (W1LDW / 8) + 4];
#pragma unroll
            for (int n = 0; n < 2; ++n) {
                f32x4 a = __builtin_amdgcn_mfma_f32_16x16x32_bf16(wM0, hb[n][0], b1q[mt], 0, 0, 0);
                aM[mt][n] = __builtin_amdgcn_mfma_f32_16x16x32_bf16(wM1, hb[n][1], a, 0, 0, 0);
            }
        }

        // ---- relu(a) -> hl cols 64..95, MLP2 via padded MFMA ----
#pragma unroll
        for (int n = 0; n < 2; ++n)
#pragma unroll
            for (int mt = 0; mt < 2; ++mt) {
                uint2 pk;
                pk.x = cvtpk(fmaxf(aM[mt][n][0], 0.f), fmaxf(aM[mt][n][1], 0.f));
                pk.y = cvtpk(fmaxf(aM[mt][n][2], 0.f), fmaxf(aM[mt][n][3], 0.f));
                *reinterpret_cast<uint2*>(&hl[(n * 16 + ln) * HLW + 64 + mt * 16 + g * 4]) = pk;
            }
        f32x4 aD[2];
#pragma unroll
        for (int n = 0; n < 2; ++n) {
            bf16x8 ab = *reinterpret_cast<const bf16x8*>(&hl[(n * 16 + ln) * HLW + 64 + g * 8]);
            aD[n] = __builtin_amdgcn_mfma_f32_16x16x32_bf16(w2f, ab, Z0, 0, 0, 0);
        }

        // ---- flow update (aD valid on g==0 lanes; 0 on g>0 so y stays finite) ----
#pragma unroll
        for (int n = 0; n < 2; ++n) {
            int rl = wave * 32 + n * 16 + ln;
            float2 xt = *reinterpret_cast<const float2*>(&XY[rl * XYW + t * 2]);
            float s0 = softplusf(aD[n][2] + b22) + 1e-6f;
            float s1 = softplusf(aD[n][3] + b23) + 1e-6f;
            y[n].x += (aD[n][0] + b20) + s0 * xt.x;
            y[n].y += (aD[n][1] + b21) + s1 * xt.y;
            if (g0)
                *reinterpret_cast<float2*>(&XY[rl * XYW + t * 2]) = y[n];
        }
    }

    __syncthreads();
    // ---- coalesced store XY -> out ----
    {
        float4* og = reinterpret_cast<float4*>(out) + (size_t)base * NF4;
        const int tot = 128 * NF4;
        for (int i = tid; i < tot; i += 256) {
            if (i < rows * NF4) {
                int r = i / NF4, c = i - r * NF4;
                og[i] = *reinterpret_cast<const float4*>(&XY[r * XYW + c * 4]);
            }
        }
    }
}

extern "C" void kernel_launch(void* const* d_in, const int* in_sizes, int n_in,
                              void* d_out, int out_size, void* d_ws, size_t ws_size,
                              hipStream_t stream) {
    const float* y_tm1 = (const float*)d_in[0];
    const float* z     = (const float*)d_in[1];
    const float* x     = (const float*)d_in[2];
    const float* Wih   = (const float*)d_in[3];
    const float* Whh   = (const float*)d_in[4];
    const float* bih   = (const float*)d_in[5];
    const float* bhh   = (const float*)d_in[6];
    const float* W1    = (const float*)d_in[7];
    const float* b1    = (const float*)d_in[8];
    const float* W2    = (const float*)d_in[9];
    const float* b2    = (const float*)d_in[10];
    float* out = (float*)d_out;
    short* wsw = (short*)d_ws;

    const int B = in_sizes[0] / 2;
    const int T = in_sizes[2] / in_sizes[0];

    hipLaunchKernelGGL(prep_kernel, dim3((WS_TOT + 255) / 256), dim3(256), 0, stream,
                       Wih, Whh, bih, bhh, W1, W2, wsw);

    const int nblk = (B + 127) / 128;
    hipLaunchKernelGGL(arflow5, dim3(nblk), dim3(256), 0, stream,
                       y_tm1, z, x, b1, b2, wsw, out, B, T);
}